// Round 7
// baseline (132.381 us; speedup 1.0000x reference)
//
#include <hip/hip_runtime.h>

// Problem constants
#define B_ 4
#define C_ 64
#define F_ 64
#define T_ 128
#define IC_ 32
#define N_ 8192
#define M_ 2048

// Scratch layout (float units; all fp32 intermediates)
// z layout is [b][o][m] (MFMA-store friendly; k3 gathers within an 8KB row)
#define OFF_U      0           // B*N                        (32768)
#define OFF_Z      32768       // B*64*M, layout [b][o][m]   (524288)
#define OFF_V      557056      // B*M
#define OFF_VS     565248      // B*M sorted v (descending)
#define OFF_Q01    573440      // B*2049*64 float2 (z-prefix, vz-prefix), [b][k][o]
#define WS_FLOATS  1622528     // 6.49 MB static device scratch

__device__ __align__(16) float g_ws[WS_FLOATS];
__device__ int g_perm[B_ * M_];

// Producer-consumer flags for the fused k3+k4 launch. MONOTONIC (never reset;
// zero-initialized at module load) -> safe across graph replays. Padded to
// 256B so the 4 per-batch counters live on separate cache lines.
__device__ unsigned g_done[B_ * 64];   // producer completions, index b*64
__device__ unsigned g_cons[B_ * 64];   // consumer tickets,     index b*64

typedef __attribute__((ext_vector_type(8))) short short8_t;
typedef __attribute__((ext_vector_type(4))) float f32x4;

__device__ __forceinline__ unsigned short f2bf(float f) {
    unsigned b = __float_as_uint(f);
    b += 0x7fffu + ((b >> 16) & 1u);        // RNE
    return (unsigned short)(b >> 16);
}
__device__ __forceinline__ float bf2f(unsigned short h) {
    return __uint_as_float(((unsigned)h) << 16);
}

// Swizzled LDS index helpers (indices in shorts; XOR bits >= 8-short granule,
// so b64/b128 blocks stay contiguous). T2-style: breaks the 16-way bank
// conflict of 128B-stride rows read column-wise by lanes 0..15.
#define XSIDX(p, c)  ((((p) * 64) + (c)) ^ (((p) & 7) << 3))    // [128][64] bf16
#define WAIDX(o, c)  ((((o) * 64) + (c)) ^ (((o) & 7) << 3))    // [64][64]  bf16
#define WZIDX(o, c)  ((((o) * 32) + (c)) ^ (((o) & 3) << 3))    // [64][32]  bf16
#define PSIDX(p, c)  ((((p) * 32) + (c)) ^ (((p) & 3) << 3))    // [32][32]  bf16

// ---------------------------------------------------------------------------
// Kernel 1 (MFMA): psi/phi conv as bf16 MFMA + in-register 2x2 pool;
// z = W_w . psi as a second MFMA; v from phi via shuffles; u from bf16 tile.
// 256 blocks x 256 thr (4 waves). Block = (b, row-pair fh, col-half hf).
// UNCHANGED from round 6 (verified at 113.5 us, absmax 1.6e-2).
// ---------------------------------------------------------------------------
__global__ __launch_bounds__(256) void k1(
    const float* __restrict__ x,
    const float* __restrict__ psi_w, const float* __restrict__ psi_b,
    const float* __restrict__ theta_w, const float* __restrict__ theta_b,
    const float* __restrict__ phi_w, const float* __restrict__ phi_b,
    const float* __restrict__ h0_w, const float* __restrict__ h1_w,
    const float* __restrict__ h2_w, const float* __restrict__ W_w)
{
    float* __restrict__ ws = g_ws;
    __shared__ __align__(16) unsigned short XS[128 * 64];  // x tile bf16 [p][c]
    __shared__ __align__(16) unsigned short WA[64 * 64];   // [psi_w; phi_w] bf16 [o][c]
    __shared__ __align__(16) unsigned short WZ[64 * 32];   // W_w cols 0..31 bf16 [o64][ic]
    __shared__ __align__(16) unsigned short PS[32 * 32];   // pooled psi bf16 [pc][ic]
    __shared__ __align__(16) float pb[64];                 // psi_b | phi_b
    __shared__ __align__(16) float h1l[32];
    __shared__ __align__(16) float wtl[64];                // sum_o h0[o]*theta_w[o][c]
    __shared__ float vtmp[2][32];

    const int tid = threadIdx.x;
    const int bid = blockIdx.x;
    const int b = bid >> 6;
    const int rem = bid & 63;
    const int fh = rem >> 1;        // row-pair [0,32)
    const int hf = rem & 1;         // col-half

    const float h20 = h2_w[0], h21 = h2_w[1];

    // ---- stage x tile: f32 -> bf16, 4x4 in-register transpose -> [p][c] ----
    for (int it = 0; it < 2; ++it) {
        const int u = it * 256 + tid;          // unit in [0,512)
        const int colq = u & 15, r = (u >> 4) & 1, cq = u >> 5;
        float4 xv[4];
#pragma unroll
        for (int j = 0; j < 4; ++j)
            xv[j] = *(const float4*)&x[(((size_t)b * 64 + (4 * cq + j)) * 64 + (2 * fh + r)) * 128 + hf * 64 + 4 * colq];
        const float* xf0 = (const float*)&xv[0];
        const float* xf1 = (const float*)&xv[1];
        const float* xf2 = (const float*)&xv[2];
        const float* xf3 = (const float*)&xv[3];
#pragma unroll
        for (int i = 0; i < 4; ++i) {
            const int p = r * 64 + 4 * colq + i;
            short4 sv;
            sv.x = (short)f2bf(xf0[i]); sv.y = (short)f2bf(xf1[i]);
            sv.z = (short)f2bf(xf2[i]); sv.w = (short)f2bf(xf3[i]);
            *(short4*)&XS[XSIDX(p, 4 * cq)] = sv;
        }
    }
    // ---- stage conv weights bf16 [o][c]: rows 0-31 psi, 32-63 phi ----
    for (int it = 0; it < 4; ++it) {
        const int f4 = it * 256 + tid;         // [0,1024)
        const int o2 = f4 >> 4;                // [0,64)
        const int cq = f4 & 15;
        const float* src = (o2 < 32) ? &psi_w[o2 * 64 + 4 * cq]
                                     : &phi_w[(o2 - 32) * 64 + 4 * cq];
        const float4 wv = *(const float4*)src;
        short4 sv;
        sv.x = (short)f2bf(wv.x); sv.y = (short)f2bf(wv.y);
        sv.z = (short)f2bf(wv.z); sv.w = (short)f2bf(wv.w);
        *(short4*)&WA[WAIDX(o2, 4 * cq)] = sv;
    }
    // ---- stage W_w (64x33, cols 0..31) bf16 [o64][ic] ----
    for (int it = 0; it < 8; ++it) {
        const int e = it * 256 + tid;          // [0,2048)
        const int o64 = e >> 5, ic = e & 31;
        WZ[WZIDX(o64, ic)] = f2bf(W_w[o64 * 33 + ic]);
    }
    if (tid < 64) pb[tid] = (tid < 32) ? psi_b[tid] : phi_b[tid - 32];
    if (tid < 32) h1l[tid] = h1_w[tid];
    if (tid < 64) {
        float acc = 0.f;
        for (int o2 = 0; o2 < 32; ++o2)
            acc += h0_w[o2] * theta_w[o2 * 64 + tid];
        wtl[tid] = acc;
    }
    __syncthreads();

    const int w = tid >> 6, lane = tid & 63;
    const int lo = lane & 15, hi = lane >> 4;

    // ---- conv MFMA: wave w owns output rows 16w..16w+15; 8 pos-tiles, K=64 ----
    short8_t a0 = *(const short8_t*)&WA[WAIDX(16 * w + lo, hi * 8)];
    short8_t a1 = *(const short8_t*)&WA[WAIDX(16 * w + lo, 32 + hi * 8)];
    f32x4 acc[8];
#pragma unroll
    for (int t = 0; t < 8; ++t) { acc[t].x = 0.f; acc[t].y = 0.f; acc[t].z = 0.f; acc[t].w = 0.f; }
#pragma unroll
    for (int t = 0; t < 8; ++t) {
        const short8_t b0 = *(const short8_t*)&XS[XSIDX(16 * t + lo, hi * 8)];
        const short8_t b1 = *(const short8_t*)&XS[XSIDX(16 * t + lo, 32 + hi * 8)];
        acc[t] = __builtin_amdgcn_mfma_f32_16x16x32_bf16(a0, b0, acc[t], 0, 0, 0);
        acc[t] = __builtin_amdgcn_mfma_f32_16x16x32_bf16(a1, b1, acc[t], 0, 0, 0);
    }

    // ---- 2x2 maxpool in-register ----
    const int isPsi = (w < 2);
    const int obase = (w & 1) * 16 + hi * 4;   // channel quad base within 32
    const int pcj = lo >> 1;
#pragma unroll
    for (int t = 0; t < 4; ++t) {
        const int pc = 8 * t + pcj;
        float pv[4];
#pragma unroll
        for (int r = 0; r < 4; ++r) {
            const float mx = fmaxf(acc[t][r], acc[t + 4][r]);
            pv[r] = fmaxf(mx, __shfl_xor(mx, 1, 64)) + pb[(isPsi ? 0 : 32) + obase + r];
        }
        if (isPsi) {
            if ((lane & 1) == 0) {
                short4 sv;
                sv.x = (short)f2bf(pv[0]); sv.y = (short)f2bf(pv[1]);
                sv.z = (short)f2bf(pv[2]); sv.w = (short)f2bf(pv[3]);
                *(short4*)&PS[PSIDX(pc, obase)] = sv;
            }
        } else {
            float hp = h1l[obase] * pv[0] + h1l[obase + 1] * pv[1]
                     + h1l[obase + 2] * pv[2] + h1l[obase + 3] * pv[3];
            hp += __shfl_xor(hp, 16, 64);
            hp += __shfl_xor(hp, 32, 64);
            if (hi == 0 && (lane & 1) == 0)
                vtmp[w - 2][pc] = hp;
        }
    }
    __syncthreads();

    // ---- v finalize ----
    if (tid < 32) {
        const int pc = tid;
        const int m = fh * 64 + hf * 32 + pc;
        const float bpos = h20 * (fh * (1.0f / 31.0f))
                         + h21 * ((hf * 32 + pc) * (1.0f / 63.0f));
        ws[OFF_V + b * 2048 + m] = vtmp[0][pc] + vtmp[1][pc] - bpos;
    }

    // ---- z MFMA: z[o64][pc] = W_w[o64][0..31] . psi[0..31][pc], K=32 ----
    {
        const short8_t az = *(const short8_t*)&WZ[WZIDX(16 * w + lo, hi * 8)];
#pragma unroll
        for (int pt = 0; pt < 2; ++pt) {
            const short8_t bz = *(const short8_t*)&PS[PSIDX(16 * pt + lo, hi * 8)];
            f32x4 zc; zc.x = 0.f; zc.y = 0.f; zc.z = 0.f; zc.w = 0.f;
            zc = __builtin_amdgcn_mfma_f32_16x16x32_bf16(az, bz, zc, 0, 0, 0);
            const int m = fh * 64 + hf * 32 + 16 * pt + lo;
#pragma unroll
            for (int r = 0; r < 4; ++r)
                ws[OFF_Z + ((size_t)b * 64 + 16 * w + hi * 4 + r) * 2048 + m] = zc[r];
        }
    }

    // ---- u: collapsed theta conv from bf16 tile; 2 threads per position ----
    {
        const int ph = tid & 1, p = tid >> 1;
        float ua = 0.f;
#pragma unroll
        for (int c4 = 0; c4 < 8; ++c4) {
            const int c = ph * 32 + c4 * 4;
            const short4 xv = *(const short4*)&XS[XSIDX(p, c)];
            const float4 wv = *(const float4*)&wtl[c];
            ua += wv.x * bf2f((unsigned short)xv.x) + wv.y * bf2f((unsigned short)xv.y)
                + wv.z * bf2f((unsigned short)xv.z) + wv.w * bf2f((unsigned short)xv.w);
        }
        ua += __shfl_xor(ua, 1, 64);
        if (ph == 0) {
            float tb_ = 0.f;
            for (int o2 = 0; o2 < 32; ++o2)
                tb_ += h0_w[o2] * theta_b[o2];
            const int f = 2 * fh + (p >> 6), tt = hf * 64 + (p & 63);
            const int n = f * 128 + tt;
            const float a = h20 * (f * (1.0f / 63.0f)) + h21 * (tt * (1.0f / 127.0f));
            ws[OFF_U + b * 8192 + n] = ua + tb_ + a;
        }
    }
}

// ---------------------------------------------------------------------------
// Kernel 2: barrier-free rank sort (descending, index tie-break) — unchanged
// ---------------------------------------------------------------------------
__global__ __launch_bounds__(256) void k2()
{
    float* __restrict__ ws = g_ws;
    __shared__ __align__(16) float vl[2048];
    __shared__ int part[256];
    const int tid = threadIdx.x;
    const int b = blockIdx.x >> 7, chunk = blockIdx.x & 127;
    const float* v = ws + OFF_V + b * 2048;
    for (int i = tid; i < 2048; i += 256) vl[i] = v[i];
    __syncthreads();

    const int ml = tid >> 4;
    const int jq = tid & 15;
    const int m = chunk * 16 + ml;
    const float vm = vl[m];
    int cnt = 0;
    const float4* v4 = (const float4*)vl;
#pragma unroll 4
    for (int i = 0; i < 32; ++i) {
        const int j4 = jq + 16 * i;
        const float4 vv = v4[j4];
        const int jb = j4 * 4;
        cnt += (vv.x > vm) || (vv.x == vm && (jb    ) < m);
        cnt += (vv.y > vm) || (vv.y == vm && (jb + 1) < m);
        cnt += (vv.z > vm) || (vv.z == vm && (jb + 2) < m);
        cnt += (vv.w > vm) || (vv.w == vm && (jb + 3) < m);
    }
    part[tid] = cnt;
    __syncthreads();
    if (tid < 16) {
        int r = 0;
#pragma unroll
        for (int j = 0; j < 16; ++j) r += part[tid * 16 + j];
        ws[OFF_VS + b * 2048 + r] = vl[chunk * 16 + tid];
        g_perm[b * 2048 + r] = chunk * 16 + tid;
    }
}

// ---------------------------------------------------------------------------
// Kernel 3+4 fused via producer-consumer flags (one launch, 768 blocks x 512).
// Blocks 0..255   = k3 role (b,o): gather z, scan -> Q01; publish done[b] via
//                   ACQ_REL fetch_add (wbl2 completes BEFORE flag visible —
//                   round-4-proven publish pattern).
// Blocks 256..767 = k4 role (b,tile): stage vs + binary-search k(n) FIRST
//                   (depends only on k1/k2), then tid0 spins RELAXED (no
//                   per-poll L2 invalidate) until done[b] >= 64*(rep+1),
//                   one ACQUIRE fence, then gather Q01 + epilogue.
// Replay-safe: counters are monotonic; consumer derives its replay index from
// a ticket on g_cons[b] (128 consumers per b per launch).
// Deadlock-free by capacity: 512 thr -> 4 blocks/CU = 1024 slots >= 768; even
// with all 512 consumers resident+spinning, >= 512 free slots hold the 256
// producers.
// ---------------------------------------------------------------------------
__global__ __launch_bounds__(512) void k34(
    const float* __restrict__ x,
    const float* __restrict__ W_b,
    const float* __restrict__ bn_g, const float* __restrict__ bn_b,
    const float* __restrict__ bn_m, const float* __restrict__ bn_v,
    float* __restrict__ out)
{
    float* __restrict__ ws = g_ws;
    __shared__ __align__(16) float vsl[2048];   // k4: sorted v | k3: unused
    __shared__ float tileb[64 * 65];            // k4 only
    __shared__ int karr[64];
    __shared__ float uarr[64];
    __shared__ float wt0[8], wt1[8];            // k3 only

    const int tid = threadIdx.x;

    if (blockIdx.x < 256) {
        // =================== k3 role: z gather + scan -> Q01 ===================
        const int b = blockIdx.x >> 6, o = blockIdx.x & 63;

        const int* perm = g_perm + b * 2048;
        const float* vs = ws + OFF_VS + b * 2048;
        const float* zg = ws + OFF_Z + ((size_t)b * 64 + o) * 2048;   // z row [m]

        float zl[4], vlv[4];
        float s0 = 0.f, s1 = 0.f;
        const int base = tid * 4;
#pragma unroll
        for (int qq = 0; qq < 4; ++qq) {
            const int i = base + qq;
            const int mp = perm[i];
            const float z = zg[mp];                 // scattered 4B in an 8KB row
            const float vv = vs[i];
            zl[qq] = z; vlv[qq] = vv;
            s0 += z; s1 += vv * z;
        }

        float w0 = s0, w1 = s1;
        const int lane = tid & 63, wv = tid >> 6;
#pragma unroll
        for (int off = 1; off < 64; off <<= 1) {
            const float t0_ = __shfl_up(w0, off, 64);
            const float t1_ = __shfl_up(w1, off, 64);
            if (lane >= off) { w0 += t0_; w1 += t1_; }
        }
        if (lane == 63) { wt0[wv] = w0; wt1[wv] = w1; }
        __syncthreads();
        float base0 = 0.f, base1 = 0.f;
        for (int w = 0; w < wv; ++w) { base0 += wt0[w]; base1 += wt1[w]; }
        float r0 = w0 + base0 - s0, r1 = w1 + base1 - s1;   // exclusive prefix

        float2* Q01 = (float2*)(ws + OFF_Q01) + (size_t)b * 2049 * 64;
#pragma unroll
        for (int qq = 0; qq < 4; ++qq) {
            r0 += zl[qq]; r1 += vlv[qq] * zl[qq];
            float2 p; p.x = r0; p.y = r1;
            Q01[(size_t)(base + qq + 1) * 64 + o] = p;
        }
        if (tid == 0) { float2 z2; z2.x = 0.f; z2.y = 0.f; Q01[o] = z2; }

        __syncthreads();   // all global stores drained (vmcnt(0) before s_barrier)
        if (tid == 0)
            __hip_atomic_fetch_add(&g_done[b * 64], 1u, __ATOMIC_ACQ_REL,
                                   __HIP_MEMORY_SCOPE_AGENT);
    } else {
        // =================== k4 role: gather + epilogue ===================
        const int idx = (int)blockIdx.x - 256;
        const int b = idx >> 7, tile = idx & 127;
        const int n0 = tile * 64;

        // --- work NOT depending on Q01: stage vs, binary search (overlaps spin) ---
        const float* vs = ws + OFF_VS + b * 2048;
        *(float4*)&vsl[tid * 4] = *(const float4*)&vs[tid * 4];
        __syncthreads();

        if (tid < 64) {
            const float u = ws[OFF_U + b * 8192 + n0 + tid];
            const float thr = -u;
            int lo = 0, hi = 2048;
            while (lo < hi) {
                const int mid = (lo + hi) >> 1;
                if (vsl[mid] > thr) lo = mid + 1; else hi = mid;
            }
            karr[tid] = lo;
            uarr[tid] = u;
        } else if (tid == 256) {
            // ticket -> replay index -> monotonic goal; RELAXED spin
            const unsigned t = __hip_atomic_fetch_add(&g_cons[b * 64], 1u,
                                                      __ATOMIC_RELAXED,
                                                      __HIP_MEMORY_SCOPE_AGENT);
            const unsigned goal = ((t >> 7) + 1u) * 64u;
            while (__hip_atomic_load(&g_done[b * 64], __ATOMIC_RELAXED,
                                     __HIP_MEMORY_SCOPE_AGENT) < goal)
                __builtin_amdgcn_s_sleep(8);
            __builtin_amdgcn_fence(__ATOMIC_ACQUIRE, "agent");   // inv stale L1/L2
        }
        __syncthreads();   // karr ready AND Q01 visible

        const int lane = tid & 63, w = tid >> 6;
        const float inv = bn_g[lane] * __frsqrt_rn(bn_v[lane] + 1e-5f);
        const float sft = W_b[lane] * inv + bn_b[lane] - bn_m[lane] * inv;
        const float2* Q01 = (const float2*)(ws + OFF_Q01) + (size_t)b * 2049 * 64;

        for (int nl = w; nl < 64; nl += 8) {
            const int k = karr[nl];
            const float u = uarr[nl];
            const float2 qv = Q01[(size_t)k * 64 + lane];
            const float raw = (u * qv.x + qv.y) * (1.0f / 2048.0f);
            tileb[lane * 65 + nl] = raw * inv + sft;
        }
        __syncthreads();

        for (int i2 = tid; i2 < 2048; i2 += 512) {
            const int o = i2 >> 5, j2 = i2 & 31;
            const size_t gi = ((size_t)b * 64 + o) * 8192 + n0 + 2 * j2;
            const float2 xv = *(const float2*)&x[gi];
            float2 r;
            r.x = tileb[o * 65 + 2 * j2] + xv.x;
            r.y = tileb[o * 65 + 2 * j2 + 1] + xv.y;
            *(float2*)&out[gi] = r;
        }
    }
}

// ---------------------------------------------------------------------------
extern "C" void kernel_launch(void* const* d_in, const int* in_sizes, int n_in,
                              void* d_out, int out_size, void* d_ws, size_t ws_size,
                              hipStream_t stream)
{
    (void)in_sizes; (void)n_in; (void)out_size; (void)d_ws; (void)ws_size;
    const float* x       = (const float*)d_in[0];
    const float* psi_w   = (const float*)d_in[1];
    const float* psi_b   = (const float*)d_in[2];
    const float* theta_w = (const float*)d_in[3];
    const float* theta_b = (const float*)d_in[4];
    const float* phi_w   = (const float*)d_in[5];
    const float* phi_b   = (const float*)d_in[6];
    const float* h0_w    = (const float*)d_in[7];
    const float* h1_w    = (const float*)d_in[8];
    const float* h2_w    = (const float*)d_in[9];
    const float* W_w     = (const float*)d_in[10];
    const float* W_b     = (const float*)d_in[11];
    const float* bn_g    = (const float*)d_in[12];
    const float* bn_b    = (const float*)d_in[13];
    const float* bn_m    = (const float*)d_in[14];
    const float* bn_v    = (const float*)d_in[15];
    float* out = (float*)d_out;

    k1<<<dim3(256), dim3(256), 0, stream>>>(x, psi_w, psi_b, theta_w, theta_b,
                                            phi_w, phi_b, h0_w, h1_w, h2_w, W_w);
    k2<<<dim3(512), dim3(256), 0, stream>>>();
    k34<<<dim3(768), dim3(512), 0, stream>>>(x, W_b, bn_g, bn_b, bn_m, bn_v, out);
}

// Round 8
// 119.726 us; speedup vs baseline: 1.1057x; 1.1057x over previous
//
#include <hip/hip_runtime.h>

// Problem constants
#define B_ 4
#define C_ 64
#define F_ 64
#define T_ 128
#define IC_ 32
#define N_ 8192
#define M_ 2048

// Scratch layout (float units; all fp32 intermediates)
// z layout is [b][o][m] (MFMA-store friendly; k3 gathers within an 8KB row)
#define OFF_U      0           // B*N                        (32768)
#define OFF_Z      32768       // B*64*M, layout [b][o][m]   (524288)
#define OFF_V      557056      // B*M
#define OFF_VS     565248      // B*M sorted v (descending)
#define OFF_Q01    573440      // B*2049*64 float2 (z-prefix, vz-prefix), [b][k][o]
#define WS_FLOATS  1622528     // 6.49 MB static device scratch

__device__ __align__(16) float g_ws[WS_FLOATS];
__device__ int g_perm[B_ * M_];

typedef __attribute__((ext_vector_type(8))) short short8_t;
typedef __attribute__((ext_vector_type(4))) float f32x4;

__device__ __forceinline__ unsigned short f2bf(float f) {
    unsigned b = __float_as_uint(f);
    b += 0x7fffu + ((b >> 16) & 1u);        // RNE
    return (unsigned short)(b >> 16);
}
__device__ __forceinline__ float bf2f(unsigned short h) {
    return __uint_as_float(((unsigned)h) << 16);
}

// Swizzled LDS index helpers (indices in shorts; XOR bits >= 8-short granule,
// so b64/b128 blocks stay contiguous). T2-style: breaks the 16-way bank
// conflict of 128B-stride rows read column-wise by lanes 0..15.
#define XSIDX(p, c)  ((((p) * 64) + (c)) ^ (((p) & 7) << 3))    // [128][64] bf16
#define WAIDX(o, c)  ((((o) * 64) + (c)) ^ (((o) & 7) << 3))    // [64][64]  bf16
#define WZIDX(o, c)  ((((o) * 32) + (c)) ^ (((o) & 3) << 3))    // [64][32]  bf16
#define PSIDX(p, c)  ((((p) * 32) + (c)) ^ (((p) & 3) << 3))    // [32][32]  bf16

// ---------------------------------------------------------------------------
// Kernel 1 (MFMA): psi/phi conv as bf16 MFMA + in-register 2x2 pool;
// z = W_w . psi as a second MFMA; v from phi via shuffles; u from bf16 tile.
// 256 blocks x 256 thr (4 waves). Block = (b, row-pair fh, col-half hf).
// UNCHANGED from round 6 (verified at 113.5 us, absmax 1.6e-2).
// ---------------------------------------------------------------------------
__global__ __launch_bounds__(256) void k1(
    const float* __restrict__ x,
    const float* __restrict__ psi_w, const float* __restrict__ psi_b,
    const float* __restrict__ theta_w, const float* __restrict__ theta_b,
    const float* __restrict__ phi_w, const float* __restrict__ phi_b,
    const float* __restrict__ h0_w, const float* __restrict__ h1_w,
    const float* __restrict__ h2_w, const float* __restrict__ W_w)
{
    float* __restrict__ ws = g_ws;
    __shared__ __align__(16) unsigned short XS[128 * 64];  // x tile bf16 [p][c]
    __shared__ __align__(16) unsigned short WA[64 * 64];   // [psi_w; phi_w] bf16 [o][c]
    __shared__ __align__(16) unsigned short WZ[64 * 32];   // W_w cols 0..31 bf16 [o64][ic]
    __shared__ __align__(16) unsigned short PS[32 * 32];   // pooled psi bf16 [pc][ic]
    __shared__ __align__(16) float pb[64];                 // psi_b | phi_b
    __shared__ __align__(16) float h1l[32];
    __shared__ __align__(16) float wtl[64];                // sum_o h0[o]*theta_w[o][c]
    __shared__ float vtmp[2][32];

    const int tid = threadIdx.x;
    const int bid = blockIdx.x;
    const int b = bid >> 6;
    const int rem = bid & 63;
    const int fh = rem >> 1;        // row-pair [0,32)
    const int hf = rem & 1;         // col-half

    const float h20 = h2_w[0], h21 = h2_w[1];

    // ---- stage x tile: f32 -> bf16, 4x4 in-register transpose -> [p][c] ----
    for (int it = 0; it < 2; ++it) {
        const int u = it * 256 + tid;          // unit in [0,512)
        const int colq = u & 15, r = (u >> 4) & 1, cq = u >> 5;
        float4 xv[4];
#pragma unroll
        for (int j = 0; j < 4; ++j)
            xv[j] = *(const float4*)&x[(((size_t)b * 64 + (4 * cq + j)) * 64 + (2 * fh + r)) * 128 + hf * 64 + 4 * colq];
        const float* xf0 = (const float*)&xv[0];
        const float* xf1 = (const float*)&xv[1];
        const float* xf2 = (const float*)&xv[2];
        const float* xf3 = (const float*)&xv[3];
#pragma unroll
        for (int i = 0; i < 4; ++i) {
            const int p = r * 64 + 4 * colq + i;
            short4 sv;
            sv.x = (short)f2bf(xf0[i]); sv.y = (short)f2bf(xf1[i]);
            sv.z = (short)f2bf(xf2[i]); sv.w = (short)f2bf(xf3[i]);
            *(short4*)&XS[XSIDX(p, 4 * cq)] = sv;
        }
    }
    // ---- stage conv weights bf16 [o][c]: rows 0-31 psi, 32-63 phi ----
    for (int it = 0; it < 4; ++it) {
        const int f4 = it * 256 + tid;         // [0,1024)
        const int o2 = f4 >> 4;                // [0,64)
        const int cq = f4 & 15;
        const float* src = (o2 < 32) ? &psi_w[o2 * 64 + 4 * cq]
                                     : &phi_w[(o2 - 32) * 64 + 4 * cq];
        const float4 wv = *(const float4*)src;
        short4 sv;
        sv.x = (short)f2bf(wv.x); sv.y = (short)f2bf(wv.y);
        sv.z = (short)f2bf(wv.z); sv.w = (short)f2bf(wv.w);
        *(short4*)&WA[WAIDX(o2, 4 * cq)] = sv;
    }
    // ---- stage W_w (64x33, cols 0..31) bf16 [o64][ic] ----
    for (int it = 0; it < 8; ++it) {
        const int e = it * 256 + tid;          // [0,2048)
        const int o64 = e >> 5, ic = e & 31;
        WZ[WZIDX(o64, ic)] = f2bf(W_w[o64 * 33 + ic]);
    }
    if (tid < 64) pb[tid] = (tid < 32) ? psi_b[tid] : phi_b[tid - 32];
    if (tid < 32) h1l[tid] = h1_w[tid];
    if (tid < 64) {
        float acc = 0.f;
        for (int o2 = 0; o2 < 32; ++o2)
            acc += h0_w[o2] * theta_w[o2 * 64 + tid];
        wtl[tid] = acc;
    }
    __syncthreads();

    const int w = tid >> 6, lane = tid & 63;
    const int lo = lane & 15, hi = lane >> 4;

    // ---- conv MFMA: wave w owns output rows 16w..16w+15; 8 pos-tiles, K=64 ----
    short8_t a0 = *(const short8_t*)&WA[WAIDX(16 * w + lo, hi * 8)];
    short8_t a1 = *(const short8_t*)&WA[WAIDX(16 * w + lo, 32 + hi * 8)];
    f32x4 acc[8];
#pragma unroll
    for (int t = 0; t < 8; ++t) { acc[t].x = 0.f; acc[t].y = 0.f; acc[t].z = 0.f; acc[t].w = 0.f; }
#pragma unroll
    for (int t = 0; t < 8; ++t) {
        const short8_t b0 = *(const short8_t*)&XS[XSIDX(16 * t + lo, hi * 8)];
        const short8_t b1 = *(const short8_t*)&XS[XSIDX(16 * t + lo, 32 + hi * 8)];
        acc[t] = __builtin_amdgcn_mfma_f32_16x16x32_bf16(a0, b0, acc[t], 0, 0, 0);
        acc[t] = __builtin_amdgcn_mfma_f32_16x16x32_bf16(a1, b1, acc[t], 0, 0, 0);
    }

    // ---- 2x2 maxpool in-register ----
    const int isPsi = (w < 2);
    const int obase = (w & 1) * 16 + hi * 4;   // channel quad base within 32
    const int pcj = lo >> 1;
#pragma unroll
    for (int t = 0; t < 4; ++t) {
        const int pc = 8 * t + pcj;
        float pv[4];
#pragma unroll
        for (int r = 0; r < 4; ++r) {
            const float mx = fmaxf(acc[t][r], acc[t + 4][r]);
            pv[r] = fmaxf(mx, __shfl_xor(mx, 1, 64)) + pb[(isPsi ? 0 : 32) + obase + r];
        }
        if (isPsi) {
            if ((lane & 1) == 0) {
                short4 sv;
                sv.x = (short)f2bf(pv[0]); sv.y = (short)f2bf(pv[1]);
                sv.z = (short)f2bf(pv[2]); sv.w = (short)f2bf(pv[3]);
                *(short4*)&PS[PSIDX(pc, obase)] = sv;
            }
        } else {
            float hp = h1l[obase] * pv[0] + h1l[obase + 1] * pv[1]
                     + h1l[obase + 2] * pv[2] + h1l[obase + 3] * pv[3];
            hp += __shfl_xor(hp, 16, 64);
            hp += __shfl_xor(hp, 32, 64);
            if (hi == 0 && (lane & 1) == 0)
                vtmp[w - 2][pc] = hp;
        }
    }
    __syncthreads();

    // ---- v finalize ----
    if (tid < 32) {
        const int pc = tid;
        const int m = fh * 64 + hf * 32 + pc;
        const float bpos = h20 * (fh * (1.0f / 31.0f))
                         + h21 * ((hf * 32 + pc) * (1.0f / 63.0f));
        ws[OFF_V + b * 2048 + m] = vtmp[0][pc] + vtmp[1][pc] - bpos;
    }

    // ---- z MFMA: z[o64][pc] = W_w[o64][0..31] . psi[0..31][pc], K=32 ----
    {
        const short8_t az = *(const short8_t*)&WZ[WZIDX(16 * w + lo, hi * 8)];
#pragma unroll
        for (int pt = 0; pt < 2; ++pt) {
            const short8_t bz = *(const short8_t*)&PS[PSIDX(16 * pt + lo, hi * 8)];
            f32x4 zc; zc.x = 0.f; zc.y = 0.f; zc.z = 0.f; zc.w = 0.f;
            zc = __builtin_amdgcn_mfma_f32_16x16x32_bf16(az, bz, zc, 0, 0, 0);
            const int m = fh * 64 + hf * 32 + 16 * pt + lo;
#pragma unroll
            for (int r = 0; r < 4; ++r)
                ws[OFF_Z + ((size_t)b * 64 + 16 * w + hi * 4 + r) * 2048 + m] = zc[r];
        }
    }

    // ---- u: collapsed theta conv from bf16 tile; 2 threads per position ----
    {
        const int ph = tid & 1, p = tid >> 1;
        float ua = 0.f;
#pragma unroll
        for (int c4 = 0; c4 < 8; ++c4) {
            const int c = ph * 32 + c4 * 4;
            const short4 xv = *(const short4*)&XS[XSIDX(p, c)];
            const float4 wv = *(const float4*)&wtl[c];
            ua += wv.x * bf2f((unsigned short)xv.x) + wv.y * bf2f((unsigned short)xv.y)
                + wv.z * bf2f((unsigned short)xv.z) + wv.w * bf2f((unsigned short)xv.w);
        }
        ua += __shfl_xor(ua, 1, 64);
        if (ph == 0) {
            float tb_ = 0.f;
            for (int o2 = 0; o2 < 32; ++o2)
                tb_ += h0_w[o2] * theta_b[o2];
            const int f = 2 * fh + (p >> 6), tt = hf * 64 + (p & 63);
            const int n = f * 128 + tt;
            const float a = h20 * (f * (1.0f / 63.0f)) + h21 * (tt * (1.0f / 127.0f));
            ws[OFF_U + b * 8192 + n] = ua + tb_ + a;
        }
    }
}

// ---------------------------------------------------------------------------
// Kernel 2: barrier-free rank sort (descending, index tie-break).
// RAMP TRIM vs round 6: 256 blocks x 256 thr, 2 chunks per block; v staged
// to LDS once per block (same b for both chunks by construction).
// ---------------------------------------------------------------------------
__global__ __launch_bounds__(256) void k2()
{
    float* __restrict__ ws = g_ws;
    __shared__ __align__(16) float vl[2048];
    __shared__ int part[256];
    const int tid = threadIdx.x;
    const int u0 = 2 * blockIdx.x;             // chunk unit [0,512)
    const int b = u0 >> 7;
    const float* v = ws + OFF_V + b * 2048;
    for (int i = tid; i < 2048; i += 256) vl[i] = v[i];
    __syncthreads();

    const float4* v4 = (const float4*)vl;
    for (int half = 0; half < 2; ++half) {
        const int chunk = (u0 & 127) + half;
        const int ml = tid >> 4;
        const int jq = tid & 15;
        const int m = chunk * 16 + ml;
        const float vm = vl[m];
        int cnt = 0;
#pragma unroll 4
        for (int i = 0; i < 32; ++i) {
            const int j4 = jq + 16 * i;
            const float4 vv = v4[j4];
            const int jb = j4 * 4;
            cnt += (vv.x > vm) || (vv.x == vm && (jb    ) < m);
            cnt += (vv.y > vm) || (vv.y == vm && (jb + 1) < m);
            cnt += (vv.z > vm) || (vv.z == vm && (jb + 2) < m);
            cnt += (vv.w > vm) || (vv.w == vm && (jb + 3) < m);
        }
        part[tid] = cnt;
        __syncthreads();
        if (tid < 16) {
            int r = 0;
#pragma unroll
            for (int j = 0; j < 16; ++j) r += part[tid * 16 + j];
            ws[OFF_VS + b * 2048 + r] = vl[chunk * 16 + tid];
            g_perm[b * 2048 + r] = chunk * 16 + tid;
        }
        __syncthreads();   // part[] reuse next half
    }
}

// ---------------------------------------------------------------------------
// Kernel 3: gather z ([b][o][m]), scan -> Q01[b][k][o] — unchanged (round 6)
// ---------------------------------------------------------------------------
__global__ __launch_bounds__(512) void k3()
{
    float* __restrict__ ws = g_ws;
    __shared__ float wt0[8], wt1[8];
    const int tid = threadIdx.x;
    const int b = blockIdx.x >> 6, o = blockIdx.x & 63;

    const int* perm = g_perm + b * 2048;
    const float* vs = ws + OFF_VS + b * 2048;
    const float* zg = ws + OFF_Z + ((size_t)b * 64 + o) * 2048;   // z row [m]

    float zl[4], vlv[4];
    float s0 = 0.f, s1 = 0.f;
    const int base = tid * 4;
#pragma unroll
    for (int qq = 0; qq < 4; ++qq) {
        const int i = base + qq;
        const int mp = perm[i];
        const float z = zg[mp];                 // scattered 4B in an 8KB row
        const float vv = vs[i];
        zl[qq] = z; vlv[qq] = vv;
        s0 += z; s1 += vv * z;
    }

    float w0 = s0, w1 = s1;
    const int lane = tid & 63, wv = tid >> 6;
#pragma unroll
    for (int off = 1; off < 64; off <<= 1) {
        const float t0_ = __shfl_up(w0, off, 64);
        const float t1_ = __shfl_up(w1, off, 64);
        if (lane >= off) { w0 += t0_; w1 += t1_; }
    }
    if (lane == 63) { wt0[wv] = w0; wt1[wv] = w1; }
    __syncthreads();
    float base0 = 0.f, base1 = 0.f;
    for (int w = 0; w < wv; ++w) { base0 += wt0[w]; base1 += wt1[w]; }
    float r0 = w0 + base0 - s0, r1 = w1 + base1 - s1;

    float2* Q01 = (float2*)(ws + OFF_Q01) + (size_t)b * 2049 * 64;
#pragma unroll
    for (int qq = 0; qq < 4; ++qq) {
        r0 += zl[qq]; r1 += vlv[qq] * zl[qq];
        float2 p; p.x = r0; p.y = r1;
        Q01[(size_t)(base + qq + 1) * 64 + o] = p;
    }
    if (tid == 0) { float2 z2; z2.x = 0.f; z2.y = 0.f; Q01[o] = z2; }
}

// ---------------------------------------------------------------------------
// Kernel 4: binary search k(n), gather Q01 rows, fold W_b+BN, add x.
// RAMP TRIM vs round 6: 256 blocks x 512 thr, 2 tiles per block; sorted v
// staged once (same b both tiles).
// ---------------------------------------------------------------------------
__global__ __launch_bounds__(512) void k4(
    const float* __restrict__ x,
    const float* __restrict__ W_b,
    const float* __restrict__ bn_g, const float* __restrict__ bn_b,
    const float* __restrict__ bn_m, const float* __restrict__ bn_v,
    float* __restrict__ out)
{
    const float* __restrict__ ws = g_ws;
    __shared__ __align__(16) float vsl[2048];
    __shared__ float tileb[64 * 65];
    __shared__ int karr[64];
    __shared__ float uarr[64];

    const int tid = threadIdx.x;
    const int u0 = 2 * blockIdx.x;             // tile unit [0,512)
    const int b = u0 >> 7;

    const float* vs = ws + OFF_VS + b * 2048;
    *(float4*)&vsl[tid * 4] = *(const float4*)&vs[tid * 4];   // 512 thr x 16B

    const int lane = tid & 63, w = tid >> 6;   // w in [0,8)
    const float inv = bn_g[lane] * __frsqrt_rn(bn_v[lane] + 1e-5f);
    const float sft = W_b[lane] * inv + bn_b[lane] - bn_m[lane] * inv;
    const float2* Q01 = (const float2*)(ws + OFF_Q01) + (size_t)b * 2049 * 64;
    __syncthreads();

    for (int half = 0; half < 2; ++half) {
        const int tile = (u0 & 127) + half;
        const int n0 = tile * 64;

        if (tid < 64) {
            const float u = ws[OFF_U + b * 8192 + n0 + tid];
            const float thr = -u;
            int lo = 0, hi = 2048;
            while (lo < hi) {                  // first idx with vsl[idx] <= -u (descending)
                const int mid = (lo + hi) >> 1;
                if (vsl[mid] > thr) lo = mid + 1; else hi = mid;
            }
            karr[tid] = lo;
            uarr[tid] = u;
        }
        __syncthreads();

        for (int nl = w; nl < 64; nl += 8) {
            const int k = karr[nl];
            const float u = uarr[nl];
            const float2 qv = Q01[(size_t)k * 64 + lane];  // 512B coalesced row
            const float raw = (u * qv.x + qv.y) * (1.0f / 2048.0f);
            tileb[lane * 65 + nl] = raw * inv + sft;       // 2-way bank aliasing: free
        }
        __syncthreads();

        for (int idx = tid; idx < 2048; idx += 512) {      // float2 epilogue
            const int o = idx >> 5, j2 = idx & 31;
            const size_t gi = ((size_t)b * 64 + o) * 8192 + n0 + 2 * j2;
            const float2 xv = *(const float2*)&x[gi];
            float2 r;
            r.x = tileb[o * 65 + 2 * j2] + xv.x;
            r.y = tileb[o * 65 + 2 * j2 + 1] + xv.y;
            *(float2*)&out[gi] = r;
        }
        __syncthreads();   // karr/tileb reuse next half
    }
}

// ---------------------------------------------------------------------------
extern "C" void kernel_launch(void* const* d_in, const int* in_sizes, int n_in,
                              void* d_out, int out_size, void* d_ws, size_t ws_size,
                              hipStream_t stream)
{
    (void)in_sizes; (void)n_in; (void)out_size; (void)d_ws; (void)ws_size;
    const float* x       = (const float*)d_in[0];
    const float* psi_w   = (const float*)d_in[1];
    const float* psi_b   = (const float*)d_in[2];
    const float* theta_w = (const float*)d_in[3];
    const float* theta_b = (const float*)d_in[4];
    const float* phi_w   = (const float*)d_in[5];
    const float* phi_b   = (const float*)d_in[6];
    const float* h0_w    = (const float*)d_in[7];
    const float* h1_w    = (const float*)d_in[8];
    const float* h2_w    = (const float*)d_in[9];
    const float* W_w     = (const float*)d_in[10];
    const float* W_b     = (const float*)d_in[11];
    const float* bn_g    = (const float*)d_in[12];
    const float* bn_b    = (const float*)d_in[13];
    const float* bn_m    = (const float*)d_in[14];
    const float* bn_v    = (const float*)d_in[15];
    float* out = (float*)d_out;

    k1<<<dim3(256), dim3(256), 0, stream>>>(x, psi_w, psi_b, theta_w, theta_b,
                                            phi_w, phi_b, h0_w, h1_w, h2_w, W_w);
    k2<<<dim3(256), dim3(256), 0, stream>>>();
    k3<<<dim3(256), dim3(512), 0, stream>>>();
    k4<<<dim3(256), dim3(512), 0, stream>>>(x, W_b, bn_g, bn_b, bn_m, bn_v, out);
}

// Round 9
// 114.889 us; speedup vs baseline: 1.1522x; 1.0421x over previous
//
#include <hip/hip_runtime.h>

// Problem constants
#define B_ 4
#define C_ 64
#define F_ 64
#define T_ 128
#define IC_ 32
#define N_ 8192
#define M_ 2048

// Scratch layout (float units; all fp32 intermediates)
// z layout is [b][o][m] (MFMA-store friendly; k3 gathers within an 8KB row)
#define OFF_U      0           // B*N                        (32768)
#define OFF_Z      32768       // B*64*M, layout [b][o][m]   (524288)
#define OFF_V      557056      // B*M
#define OFF_VS     565248      // B*M sorted v (descending)
#define OFF_Q01    573440      // B*2049*64 float2 (z-prefix, vz-prefix), [b][k][o]
#define WS_FLOATS  1622528     // 6.49 MB static device scratch

__device__ __align__(16) float g_ws[WS_FLOATS];
__device__ int g_perm[B_ * M_];

typedef __attribute__((ext_vector_type(8))) short short8_t;
typedef __attribute__((ext_vector_type(4))) float f32x4;

__device__ __forceinline__ unsigned short f2bf(float f) {
    unsigned b = __float_as_uint(f);
    b += 0x7fffu + ((b >> 16) & 1u);        // RNE
    return (unsigned short)(b >> 16);
}
__device__ __forceinline__ float bf2f(unsigned short h) {
    return __uint_as_float(((unsigned)h) << 16);
}

// Swizzled LDS index helpers (indices in shorts; XOR bits >= 8-short granule,
// so b64/b128 blocks stay contiguous). T2-style: breaks the 16-way bank
// conflict of 128B-stride rows read column-wise by lanes 0..15.
#define XSIDX(p, c)  ((((p) * 64) + (c)) ^ (((p) & 7) << 3))    // [128][64] bf16
#define WAIDX(o, c)  ((((o) * 64) + (c)) ^ (((o) & 7) << 3))    // [64][64]  bf16
#define WZIDX(o, c)  ((((o) * 32) + (c)) ^ (((o) & 3) << 3))    // [64][32]  bf16
#define PSIDX(p, c)  ((((p) * 32) + (c)) ^ (((p) & 3) << 3))    // [32][32]  bf16

// ---------------------------------------------------------------------------
// Kernel 1 (MFMA): psi/phi conv as bf16 MFMA + in-register 2x2 pool;
// z = W_w . psi as a second MFMA; v from phi via shuffles; u from bf16 tile.
// 256 blocks x 256 thr (4 waves). Block = (b, row-pair fh, col-half hf).
// EXACT round-6 version (verified 113.5 us, absmax 1.6e-2).
// ---------------------------------------------------------------------------
__global__ __launch_bounds__(256) void k1(
    const float* __restrict__ x,
    const float* __restrict__ psi_w, const float* __restrict__ psi_b,
    const float* __restrict__ theta_w, const float* __restrict__ theta_b,
    const float* __restrict__ phi_w, const float* __restrict__ phi_b,
    const float* __restrict__ h0_w, const float* __restrict__ h1_w,
    const float* __restrict__ h2_w, const float* __restrict__ W_w)
{
    float* __restrict__ ws = g_ws;
    __shared__ __align__(16) unsigned short XS[128 * 64];  // x tile bf16 [p][c]
    __shared__ __align__(16) unsigned short WA[64 * 64];   // [psi_w; phi_w] bf16 [o][c]
    __shared__ __align__(16) unsigned short WZ[64 * 32];   // W_w cols 0..31 bf16 [o64][ic]
    __shared__ __align__(16) unsigned short PS[32 * 32];   // pooled psi bf16 [pc][ic]
    __shared__ __align__(16) float pb[64];                 // psi_b | phi_b
    __shared__ __align__(16) float h1l[32];
    __shared__ __align__(16) float wtl[64];                // sum_o h0[o]*theta_w[o][c]
    __shared__ float vtmp[2][32];

    const int tid = threadIdx.x;
    const int bid = blockIdx.x;
    const int b = bid >> 6;
    const int rem = bid & 63;
    const int fh = rem >> 1;        // row-pair [0,32)
    const int hf = rem & 1;         // col-half

    const float h20 = h2_w[0], h21 = h2_w[1];

    // ---- stage x tile: f32 -> bf16, 4x4 in-register transpose -> [p][c] ----
    for (int it = 0; it < 2; ++it) {
        const int u = it * 256 + tid;          // unit in [0,512)
        const int colq = u & 15, r = (u >> 4) & 1, cq = u >> 5;
        float4 xv[4];
#pragma unroll
        for (int j = 0; j < 4; ++j)
            xv[j] = *(const float4*)&x[(((size_t)b * 64 + (4 * cq + j)) * 64 + (2 * fh + r)) * 128 + hf * 64 + 4 * colq];
        const float* xf0 = (const float*)&xv[0];
        const float* xf1 = (const float*)&xv[1];
        const float* xf2 = (const float*)&xv[2];
        const float* xf3 = (const float*)&xv[3];
#pragma unroll
        for (int i = 0; i < 4; ++i) {
            const int p = r * 64 + 4 * colq + i;
            short4 sv;
            sv.x = (short)f2bf(xf0[i]); sv.y = (short)f2bf(xf1[i]);
            sv.z = (short)f2bf(xf2[i]); sv.w = (short)f2bf(xf3[i]);
            *(short4*)&XS[XSIDX(p, 4 * cq)] = sv;
        }
    }
    // ---- stage conv weights bf16 [o][c]: rows 0-31 psi, 32-63 phi ----
    for (int it = 0; it < 4; ++it) {
        const int f4 = it * 256 + tid;         // [0,1024)
        const int o2 = f4 >> 4;                // [0,64)
        const int cq = f4 & 15;
        const float* src = (o2 < 32) ? &psi_w[o2 * 64 + 4 * cq]
                                     : &phi_w[(o2 - 32) * 64 + 4 * cq];
        const float4 wv = *(const float4*)src;
        short4 sv;
        sv.x = (short)f2bf(wv.x); sv.y = (short)f2bf(wv.y);
        sv.z = (short)f2bf(wv.z); sv.w = (short)f2bf(wv.w);
        *(short4*)&WA[WAIDX(o2, 4 * cq)] = sv;
    }
    // ---- stage W_w (64x33, cols 0..31) bf16 [o64][ic] ----
    for (int it = 0; it < 8; ++it) {
        const int e = it * 256 + tid;          // [0,2048)
        const int o64 = e >> 5, ic = e & 31;
        WZ[WZIDX(o64, ic)] = f2bf(W_w[o64 * 33 + ic]);
    }
    if (tid < 64) pb[tid] = (tid < 32) ? psi_b[tid] : phi_b[tid - 32];
    if (tid < 32) h1l[tid] = h1_w[tid];
    if (tid < 64) {
        float acc = 0.f;
        for (int o2 = 0; o2 < 32; ++o2)
            acc += h0_w[o2] * theta_w[o2 * 64 + tid];
        wtl[tid] = acc;
    }
    __syncthreads();

    const int w = tid >> 6, lane = tid & 63;
    const int lo = lane & 15, hi = lane >> 4;

    // ---- conv MFMA: wave w owns output rows 16w..16w+15; 8 pos-tiles, K=64 ----
    short8_t a0 = *(const short8_t*)&WA[WAIDX(16 * w + lo, hi * 8)];
    short8_t a1 = *(const short8_t*)&WA[WAIDX(16 * w + lo, 32 + hi * 8)];
    f32x4 acc[8];
#pragma unroll
    for (int t = 0; t < 8; ++t) { acc[t].x = 0.f; acc[t].y = 0.f; acc[t].z = 0.f; acc[t].w = 0.f; }
#pragma unroll
    for (int t = 0; t < 8; ++t) {
        const short8_t b0 = *(const short8_t*)&XS[XSIDX(16 * t + lo, hi * 8)];
        const short8_t b1 = *(const short8_t*)&XS[XSIDX(16 * t + lo, 32 + hi * 8)];
        acc[t] = __builtin_amdgcn_mfma_f32_16x16x32_bf16(a0, b0, acc[t], 0, 0, 0);
        acc[t] = __builtin_amdgcn_mfma_f32_16x16x32_bf16(a1, b1, acc[t], 0, 0, 0);
    }

    // ---- 2x2 maxpool in-register ----
    const int isPsi = (w < 2);
    const int obase = (w & 1) * 16 + hi * 4;   // channel quad base within 32
    const int pcj = lo >> 1;
#pragma unroll
    for (int t = 0; t < 4; ++t) {
        const int pc = 8 * t + pcj;
        float pv[4];
#pragma unroll
        for (int r = 0; r < 4; ++r) {
            const float mx = fmaxf(acc[t][r], acc[t + 4][r]);
            pv[r] = fmaxf(mx, __shfl_xor(mx, 1, 64)) + pb[(isPsi ? 0 : 32) + obase + r];
        }
        if (isPsi) {
            if ((lane & 1) == 0) {
                short4 sv;
                sv.x = (short)f2bf(pv[0]); sv.y = (short)f2bf(pv[1]);
                sv.z = (short)f2bf(pv[2]); sv.w = (short)f2bf(pv[3]);
                *(short4*)&PS[PSIDX(pc, obase)] = sv;
            }
        } else {
            float hp = h1l[obase] * pv[0] + h1l[obase + 1] * pv[1]
                     + h1l[obase + 2] * pv[2] + h1l[obase + 3] * pv[3];
            hp += __shfl_xor(hp, 16, 64);
            hp += __shfl_xor(hp, 32, 64);
            if (hi == 0 && (lane & 1) == 0)
                vtmp[w - 2][pc] = hp;
        }
    }
    __syncthreads();

    // ---- v finalize ----
    if (tid < 32) {
        const int pc = tid;
        const int m = fh * 64 + hf * 32 + pc;
        const float bpos = h20 * (fh * (1.0f / 31.0f))
                         + h21 * ((hf * 32 + pc) * (1.0f / 63.0f));
        ws[OFF_V + b * 2048 + m] = vtmp[0][pc] + vtmp[1][pc] - bpos;
    }

    // ---- z MFMA: z[o64][pc] = W_w[o64][0..31] . psi[0..31][pc], K=32 ----
    {
        const short8_t az = *(const short8_t*)&WZ[WZIDX(16 * w + lo, hi * 8)];
#pragma unroll
        for (int pt = 0; pt < 2; ++pt) {
            const short8_t bz = *(const short8_t*)&PS[PSIDX(16 * pt + lo, hi * 8)];
            f32x4 zc; zc.x = 0.f; zc.y = 0.f; zc.z = 0.f; zc.w = 0.f;
            zc = __builtin_amdgcn_mfma_f32_16x16x32_bf16(az, bz, zc, 0, 0, 0);
            const int m = hf * 32 + fh * 64 + 16 * pt + lo;
#pragma unroll
            for (int r = 0; r < 4; ++r)
                ws[OFF_Z + ((size_t)b * 64 + 16 * w + hi * 4 + r) * 2048 + m] = zc[r];
        }
    }

    // ---- u: collapsed theta conv from bf16 tile; 2 threads per position ----
    {
        const int ph = tid & 1, p = tid >> 1;
        float ua = 0.f;
#pragma unroll
        for (int c4 = 0; c4 < 8; ++c4) {
            const int c = ph * 32 + c4 * 4;
            const short4 xv = *(const short4*)&XS[XSIDX(p, c)];
            const float4 wv = *(const float4*)&wtl[c];
            ua += wv.x * bf2f((unsigned short)xv.x) + wv.y * bf2f((unsigned short)xv.y)
                + wv.z * bf2f((unsigned short)xv.z) + wv.w * bf2f((unsigned short)xv.w);
        }
        ua += __shfl_xor(ua, 1, 64);
        if (ph == 0) {
            float tb_ = 0.f;
            for (int o2 = 0; o2 < 32; ++o2)
                tb_ += h0_w[o2] * theta_b[o2];
            const int f = 2 * fh + (p >> 6), tt = hf * 64 + (p & 63);
            const int n = f * 128 + tt;
            const float a = h20 * (f * (1.0f / 63.0f)) + h21 * (tt * (1.0f / 127.0f));
            ws[OFF_U + b * 8192 + n] = ua + tb_ + a;
        }
    }
}

// ---------------------------------------------------------------------------
// Kernel 2: barrier-free rank sort (descending, index tie-break).
// EXACT round-6 version: 512 blocks x 256 thr, one chunk of 16 m's per block.
// ---------------------------------------------------------------------------
__global__ __launch_bounds__(256) void k2()
{
    float* __restrict__ ws = g_ws;
    __shared__ __align__(16) float vl[2048];
    __shared__ int part[256];
    const int tid = threadIdx.x;
    const int b = blockIdx.x >> 7, chunk = blockIdx.x & 127;
    const float* v = ws + OFF_V + b * 2048;
    for (int i = tid; i < 2048; i += 256) vl[i] = v[i];
    __syncthreads();

    const int ml = tid >> 4;
    const int jq = tid & 15;
    const int m = chunk * 16 + ml;
    const float vm = vl[m];
    int cnt = 0;
    const float4* v4 = (const float4*)vl;
#pragma unroll 4
    for (int i = 0; i < 32; ++i) {
        const int j4 = jq + 16 * i;
        const float4 vv = v4[j4];
        const int jb = j4 * 4;
        cnt += (vv.x > vm) || (vv.x == vm && (jb    ) < m);
        cnt += (vv.y > vm) || (vv.y == vm && (jb + 1) < m);
        cnt += (vv.z > vm) || (vv.z == vm && (jb + 2) < m);
        cnt += (vv.w > vm) || (vv.w == vm && (jb + 3) < m);
    }
    part[tid] = cnt;
    __syncthreads();
    if (tid < 16) {
        int r = 0;
#pragma unroll
        for (int j = 0; j < 16; ++j) r += part[tid * 16 + j];
        ws[OFF_VS + b * 2048 + r] = vl[chunk * 16 + tid];
        g_perm[b * 2048 + r] = chunk * 16 + tid;
    }
}

// ---------------------------------------------------------------------------
// Kernel 3: gather z ([b][o][m]), scan -> Q01[b][k][o] — EXACT round-6 version
// ---------------------------------------------------------------------------
__global__ __launch_bounds__(512) void k3()
{
    float* __restrict__ ws = g_ws;
    __shared__ float wt0[8], wt1[8];
    const int tid = threadIdx.x;
    const int b = blockIdx.x >> 6, o = blockIdx.x & 63;

    const int* perm = g_perm + b * 2048;
    const float* vs = ws + OFF_VS + b * 2048;
    const float* zg = ws + OFF_Z + ((size_t)b * 64 + o) * 2048;   // z row [m]

    float zl[4], vlv[4];
    float s0 = 0.f, s1 = 0.f;
    const int base = tid * 4;
#pragma unroll
    for (int qq = 0; qq < 4; ++qq) {
        const int i = base + qq;
        const int mp = perm[i];
        const float z = zg[mp];                 // scattered 4B in an 8KB row
        const float vv = vs[i];
        zl[qq] = z; vlv[qq] = vv;
        s0 += z; s1 += vv * z;
    }

    float w0 = s0, w1 = s1;
    const int lane = tid & 63, wv = tid >> 6;
#pragma unroll
    for (int off = 1; off < 64; off <<= 1) {
        const float t0_ = __shfl_up(w0, off, 64);
        const float t1_ = __shfl_up(w1, off, 64);
        if (lane >= off) { w0 += t0_; w1 += t1_; }
    }
    if (lane == 63) { wt0[wv] = w0; wt1[wv] = w1; }
    __syncthreads();
    float base0 = 0.f, base1 = 0.f;
    for (int w = 0; w < wv; ++w) { base0 += wt0[w]; base1 += wt1[w]; }
    float r0 = w0 + base0 - s0, r1 = w1 + base1 - s1;

    float2* Q01 = (float2*)(ws + OFF_Q01) + (size_t)b * 2049 * 64;
#pragma unroll
    for (int qq = 0; qq < 4; ++qq) {
        r0 += zl[qq]; r1 += vlv[qq] * zl[qq];
        float2 p; p.x = r0; p.y = r1;
        Q01[(size_t)(base + qq + 1) * 64 + o] = p;
    }
    if (tid == 0) { float2 z2; z2.x = 0.f; z2.y = 0.f; Q01[o] = z2; }
}

// ---------------------------------------------------------------------------
// Kernel 4: binary search k(n), gather Q01 rows, fold W_b+BN, add x.
// EXACT round-6 version: 512 blocks x 512 thr, one 64-col tile per block.
// ---------------------------------------------------------------------------
__global__ __launch_bounds__(512) void k4(
    const float* __restrict__ x,
    const float* __restrict__ W_b,
    const float* __restrict__ bn_g, const float* __restrict__ bn_b,
    const float* __restrict__ bn_m, const float* __restrict__ bn_v,
    float* __restrict__ out)
{
    const float* __restrict__ ws = g_ws;
    __shared__ __align__(16) float vsl[2048];
    __shared__ float tileb[64 * 65];
    __shared__ int karr[64];
    __shared__ float uarr[64];

    const int tid = threadIdx.x;
    const int b = blockIdx.x >> 7, tile = blockIdx.x & 127;
    const int n0 = tile * 64;

    const float* vs = ws + OFF_VS + b * 2048;
    *(float4*)&vsl[tid * 4] = *(const float4*)&vs[tid * 4];
    __syncthreads();

    if (tid < 64) {
        const float u = ws[OFF_U + b * 8192 + n0 + tid];
        const float thr = -u;
        int lo = 0, hi = 2048;
        while (lo < hi) {
            const int mid = (lo + hi) >> 1;
            if (vsl[mid] > thr) lo = mid + 1; else hi = mid;
        }
        karr[tid] = lo;
        uarr[tid] = u;
    }
    __syncthreads();

    const int lane = tid & 63, w = tid >> 6;
    const float inv = bn_g[lane] * __frsqrt_rn(bn_v[lane] + 1e-5f);
    const float sft = W_b[lane] * inv + bn_b[lane] - bn_m[lane] * inv;
    const float2* Q01 = (const float2*)(ws + OFF_Q01) + (size_t)b * 2049 * 64;

    for (int nl = w; nl < 64; nl += 8) {
        const int k = karr[nl];
        const float u = uarr[nl];
        const float2 qv = Q01[(size_t)k * 64 + lane];
        const float raw = (u * qv.x + qv.y) * (1.0f / 2048.0f);
        tileb[lane * 65 + nl] = raw * inv + sft;
    }
    __syncthreads();

    for (int idx = tid; idx < 2048; idx += 512) {
        const int o = idx >> 5, j2 = idx & 31;
        const size_t gi = ((size_t)b * 64 + o) * 8192 + n0 + 2 * j2;
        const float2 xv = *(const float2*)&x[gi];
        float2 r;
        r.x = tileb[o * 65 + 2 * j2] + xv.x;
        r.y = tileb[o * 65 + 2 * j2 + 1] + xv.y;
        *(float2*)&out[gi] = r;
    }
}

// ---------------------------------------------------------------------------
extern "C" void kernel_launch(void* const* d_in, const int* in_sizes, int n_in,
                              void* d_out, int out_size, void* d_ws, size_t ws_size,
                              hipStream_t stream)
{
    (void)in_sizes; (void)n_in; (void)out_size; (void)d_ws; (void)ws_size;
    const float* x       = (const float*)d_in[0];
    const float* psi_w   = (const float*)d_in[1];
    const float* psi_b   = (const float*)d_in[2];
    const float* theta_w = (const float*)d_in[3];
    const float* theta_b = (const float*)d_in[4];
    const float* phi_w   = (const float*)d_in[5];
    const float* phi_b   = (const float*)d_in[6];
    const float* h0_w    = (const float*)d_in[7];
    const float* h1_w    = (const float*)d_in[8];
    const float* h2_w    = (const float*)d_in[9];
    const float* W_w     = (const float*)d_in[10];
    const float* W_b     = (const float*)d_in[11];
    const float* bn_g    = (const float*)d_in[12];
    const float* bn_b    = (const float*)d_in[13];
    const float* bn_m    = (const float*)d_in[14];
    const float* bn_v    = (const float*)d_in[15];
    float* out = (float*)d_out;

    k1<<<dim3(256), dim3(256), 0, stream>>>(x, psi_w, psi_b, theta_w, theta_b,
                                            phi_w, phi_b, h0_w, h1_w, h2_w, W_w);
    k2<<<dim3(512), dim3(256), 0, stream>>>();
    k3<<<dim3(256), dim3(512), 0, stream>>>();
    k4<<<dim3(512), dim3(512), 0, stream>>>(x, W_b, bn_g, bn_b, bn_m, bn_v, out);
}